// Round 2
// baseline (874.096 us; speedup 1.0000x reference)
//
#include <hip/hip_runtime.h>
#include <hip/hip_fp16.h>

#define RL(x) __builtin_amdgcn_readfirstlane(x)

// ---------------- weight prep ----------------
// wt1n[(ic*8+ky)*256 + g*64 + j*8 + kx] = w1[(g*8+j)*256 + ic*64 + ky*8 + kx]   (8192)
// wt2n[((ic*4+ky)*8+ocg)*32 + o*4+kx]  = w2[(ocg*8+o)*512 + ic*16 + ky*4 + kx] (32768)
// wt3n[((ic*3+ky)*8+ocg)*24 + o*3+kx]  = w3[(ocg*8+o)*576 + ic*9  + ky*3 + kx] (36864)
__global__ __launch_bounds__(256) void wprep_k(const float* __restrict__ w1,
                                               const float* __restrict__ w2,
                                               const float* __restrict__ w3,
                                               float* __restrict__ wt1,
                                               float* __restrict__ wt2,
                                               float* __restrict__ wt3) {
  int i = blockIdx.x * 256 + threadIdx.x;
  if (i < 8192) {
    int kx = i & 7, j = (i >> 3) & 7, g = (i >> 6) & 3;
    int ky = (i >> 8) & 7, ic = i >> 11;
    wt1[i] = w1[(g * 8 + j) * 256 + ic * 64 + ky * 8 + kx];
  }
  if (i < 32768) {
    int o4 = i & 31, o = o4 >> 2, kx = o4 & 3;
    int r = i >> 5, ocg = r & 7, r2 = r >> 3, ky = r2 & 3, ic = r2 >> 2;
    wt2[i] = w2[(ocg * 8 + o) * 512 + ic * 16 + ky * 4 + kx];
  }
  if (i < 36864) {
    int o3 = i % 24, o = o3 / 3, kx = o3 - o * 3;
    int r = i / 24, ocg = r & 7, r2 = r >> 3, ky = r2 % 3, ic = r2 / 3;
    wt3[i] = w3[(ocg * 8 + o) * 576 + ic * 9 + ky * 3 + kx];
  }
}

// ---------------- conv1: x[1024,4,84,84] -> c1h[b][32*400] fp16, k=8, s=4 ----------------
// Pixels on lanes, SGPR weights. NEW: __launch_bounds__(256,2) frees VGPRs so the
// 14 float4 input loads per (ic,ky) step live in explicit A/B double buffers —
// one batched issue + counted vmcnt instead of serialized per-load waits.
__global__ __launch_bounds__(256, 2) void conv1_k(const float* __restrict__ x,
                                                  const float* __restrict__ wt,   // wt1n
                                                  const float* __restrict__ bias,
                                                  __half* __restrict__ out) {
  const int b    = blockIdx.x;
  const int tid  = threadIdx.x;
  const int lane = tid & 63;
  const int g    = RL(tid >> 6);

  int pv[7], ib[7];
#pragma unroll
  for (int s = 0; s < 7; ++s) {
    int p = lane + 64 * s;
    pv[s] = (p < 400);
    if (p > 399) p = 399;
    int py = p / 20, px = p - py * 20;
    ib[s] = py * 336 + px * 4;
  }

  float acc[7][8];
#pragma unroll
  for (int s = 0; s < 7; ++s)
#pragma unroll
    for (int j = 0; j < 8; ++j) acc[s][j] = 0.f;

  const float* xb = x + b * 28224;

#define C1_LD(av, cv, kk) do {                                                  \
    const float* rp = xb + ((kk) >> 3) * 7056 + ((kk) & 7) * 84;                \
    _Pragma("unroll") for (int s = 0; s < 7; ++s) {                             \
      av[s] = *(const float4*)(rp + ib[s]);                                     \
      cv[s] = *(const float4*)(rp + ib[s] + 4);                                 \
    }                                                                           \
  } while (0)

#define C1_CP(av, cv, kk) do {                                                  \
    const float* wp = wt + (kk) * 256 + g * 64;                                 \
    float wr[8][8];                                                             \
    _Pragma("unroll") for (int jj = 0; jj < 8; ++jj) {                          \
      float4 w0 = *(const float4*)(wp + jj * 8);                                \
      float4 w1 = *(const float4*)(wp + jj * 8 + 4);                            \
      wr[jj][0]=w0.x; wr[jj][1]=w0.y; wr[jj][2]=w0.z; wr[jj][3]=w0.w;           \
      wr[jj][4]=w1.x; wr[jj][5]=w1.y; wr[jj][6]=w1.z; wr[jj][7]=w1.w;           \
    }                                                                           \
    _Pragma("unroll") for (int s = 0; s < 7; ++s) {                             \
      float in8[8] = {av[s].x, av[s].y, av[s].z, av[s].w,                       \
                      cv[s].x, cv[s].y, cv[s].z, cv[s].w};                      \
      _Pragma("unroll") for (int jj = 0; jj < 8; ++jj)                          \
        _Pragma("unroll") for (int kx = 0; kx < 8; ++kx)                        \
          acc[s][jj] = fmaf(in8[kx], wr[jj][kx], acc[s][jj]);                   \
    }                                                                           \
  } while (0)

  float4 a0[7], c0[7], a1[7], c1v[7];
  C1_LD(a0, c0, 0);
#pragma unroll 1
  for (int k2 = 0; k2 < 16; ++k2) {
    const int k = 2 * k2;
    C1_LD(a1, c1v, k + 1);          // prefetch k+1 (in flight during compute k)
    C1_CP(a0, c0, k);
    if (k2 < 15) C1_LD(a0, c0, k + 2);  // prefetch k+2
    C1_CP(a1, c1v, k + 1);
  }
#undef C1_LD
#undef C1_CP

  const float inv256 = 1.0f / 256.0f;
#pragma unroll
  for (int j = 0; j < 8; ++j) {
    float bj = bias[g * 8 + j];
    __half* op = out + (b * 32 + g * 8 + j) * 400;
#pragma unroll
    for (int s = 0; s < 7; ++s) {
      if (pv[s]) {
        float v = acc[s][j] * inv256 + bj;
        op[lane + 64 * s] = __float2half(v > 0.f ? v : 0.f);
      }
    }
  }
}

// ---------------- t1: transpose c1h[1024][12800] -> c1t[12800][1024] (fp16) ----------------
__global__ __launch_bounds__(256) void t1_k(const __half* __restrict__ in,
                                            __half* __restrict__ out) {
  __shared__ __half t[64][65];
  const int kb = blockIdx.x * 64;   // 200 tiles
  const int bb = blockIdx.y * 64;   // 16 tiles
  const int lane = threadIdx.x & 63;
  const int ty   = threadIdx.x >> 6;
#pragma unroll
  for (int r = ty; r < 64; r += 4)
    t[r][lane] = in[(bb + r) * 12800 + kb + lane];
  __syncthreads();
#pragma unroll
  for (int r = ty; r < 64; r += 4)
    out[(kb + r) * 1024 + bb + lane] = t[lane][r];
}

// ---------------- conv2: c1t[12800][1024] -> c2t[5184][1024], k=4, s=2 (fp16 io) ----------
// Batch on lanes, 4 oc/wave. NEW: per-ic the 4 needed rows are an 80-element
// contiguous k-slab -> batched 80-load issue, A/B double-buffered across ic.
__global__ __launch_bounds__(64, 2) void conv2_k(const __half* __restrict__ in,
                                                 const float* __restrict__ wt,   // wt2n
                                                 const float* __restrict__ bias,
                                                 __half* __restrict__ out) {
  const int bid = blockIdx.x;            // 2304 = (bg*9 + opy)*16 + ocg
  const int ocg = bid & 15;
  const int r   = bid >> 4;
  const int opy = r % 9;
  const int bg  = r / 9;
  const int lane = threadIdx.x;

  float acc[4][9];
#pragma unroll
  for (int o = 0; o < 4; ++o)
#pragma unroll
    for (int ox = 0; ox < 9; ++ox) acc[o][ox] = 0.f;

  const __half* ib = in + bg * 64 + lane;
  const int kbase = 2 * opy * 20;        // rows 2*opy .. 2*opy+3 are k-contiguous

#define C2_LD(buf, icv) do {                                                    \
    const __half* rp = ib + ((icv) * 400 + kbase) * 1024;                       \
    _Pragma("unroll") for (int q = 0; q < 80; ++q) buf[q] = rp[q * 1024];       \
  } while (0)

#define C2_CP(buf, icv) do {                                                    \
    _Pragma("unroll") for (int ky = 0; ky < 4; ++ky) {                          \
      const float* wp = wt + (((icv) * 4 + ky) * 8 + (ocg >> 1)) * 32           \
                        + (ocg & 1) * 16;                                       \
      float wk[16];                                                             \
      _Pragma("unroll") for (int q = 0; q < 16; ++q) wk[q] = wp[q];             \
      float iv[20];                                                             \
      _Pragma("unroll") for (int q = 0; q < 20; ++q)                            \
        iv[q] = __half2float(buf[ky * 20 + q]);                                 \
      _Pragma("unroll") for (int o = 0; o < 4; ++o)                             \
        _Pragma("unroll") for (int ox = 0; ox < 9; ++ox)                        \
          _Pragma("unroll") for (int kx = 0; kx < 4; ++kx)                      \
            acc[o][ox] = fmaf(iv[2 * ox + kx], wk[o * 4 + kx], acc[o][ox]);     \
    }                                                                           \
  } while (0)

  __half A[80], Bq[80];
  C2_LD(A, 0);
#pragma unroll 1
  for (int i2 = 0; i2 < 16; ++i2) {
    const int ic = 2 * i2;
    C2_LD(Bq, ic + 1);
    C2_CP(A, ic);
    if (i2 < 15) C2_LD(A, ic + 2);
    C2_CP(Bq, ic + 1);
  }
#undef C2_LD
#undef C2_CP

#pragma unroll
  for (int o = 0; o < 4; ++o) {
    const int oc = ocg * 4 + o;
    const float bj = bias[oc];
#pragma unroll
    for (int ox = 0; ox < 9; ++ox) {
      float v = acc[o][ox] + bj;
      out[(oc * 81 + opy * 9 + ox) * 1024 + bg * 64 + lane] =
          __float2half(v > 0.f ? v : 0.f);
    }
  }
}

// ---------------- conv3: c2t[5184][1024] -> c3t[3136][1024], k=3, s=1 (fp16 io) ----------
__global__ __launch_bounds__(64, 2) void conv3_k(const __half* __restrict__ in,
                                                 const float* __restrict__ wt,   // wt3n
                                                 const float* __restrict__ bias,
                                                 __half* __restrict__ out) {
  const int bid = blockIdx.x;            // 1792 = (bg*7 + opy)*16 + ocg
  const int ocg = bid & 15;
  const int r   = bid >> 4;
  const int opy = r % 7;
  const int bg  = r / 7;
  const int lane = threadIdx.x;

  float acc[4][7];
#pragma unroll
  for (int o = 0; o < 4; ++o)
#pragma unroll
    for (int ox = 0; ox < 7; ++ox) acc[o][ox] = 0.f;

  const __half* ib = in + bg * 64 + lane;
  const int kbase = opy * 9;             // rows opy..opy+2 are k-contiguous (27)

#define C3_LD(buf, icv) do {                                                    \
    const __half* rp = ib + ((icv) * 81 + kbase) * 1024;                        \
    _Pragma("unroll") for (int q = 0; q < 27; ++q) buf[q] = rp[q * 1024];       \
  } while (0)

#define C3_CP(buf, icv) do {                                                    \
    _Pragma("unroll") for (int ky = 0; ky < 3; ++ky) {                          \
      const float* wp = wt + (((icv) * 3 + ky) * 8 + (ocg >> 1)) * 24           \
                        + (ocg & 1) * 12;                                       \
      float wk[12];                                                             \
      _Pragma("unroll") for (int q = 0; q < 12; ++q) wk[q] = wp[q];             \
      float iv[9];                                                              \
      _Pragma("unroll") for (int q = 0; q < 9; ++q)                             \
        iv[q] = __half2float(buf[ky * 9 + q]);                                  \
      _Pragma("unroll") for (int o = 0; o < 4; ++o)                             \
        _Pragma("unroll") for (int ox = 0; ox < 7; ++ox)                        \
          _Pragma("unroll") for (int kx = 0; kx < 3; ++kx)                      \
            acc[o][ox] = fmaf(iv[ox + kx], wk[o * 3 + kx], acc[o][ox]);         \
    }                                                                           \
  } while (0)

  __half A[27], Bq[27];
  C3_LD(A, 0);
#pragma unroll 1
  for (int i2 = 0; i2 < 32; ++i2) {
    const int ic = 2 * i2;
    C3_LD(Bq, ic + 1);
    C3_CP(A, ic);
    if (i2 < 31) C3_LD(A, ic + 2);
    C3_CP(Bq, ic + 1);
  }
#undef C3_LD
#undef C3_CP

#pragma unroll
  for (int o = 0; o < 4; ++o) {
    const int oc = ocg * 4 + o;
    const float bj = bias[oc];
#pragma unroll
    for (int ox = 0; ox < 7; ++ox) {
      float v = acc[o][ox] + bj;
      out[(oc * 49 + opy * 7 + ox) * 1024 + bg * 64 + lane] =
          __float2half(v > 0.f ? v : 0.f);
    }
  }
}

// ---------------- fc1a: c3t[3136][1024] @ fw1[3136][256] -> part[8][256][1024] ------------
__global__ __launch_bounds__(64, 2) void fc1a_k(const __half* __restrict__ a,
                                                const float* __restrict__ w,
                                                float* __restrict__ part) {
  const int bid = blockIdx.x;            // 2048 = (bg*16 + jg)*8 + kc
  const int kc = bid & 7;
  const int r  = bid >> 3;
  const int jg = r & 15;
  const int bg = r >> 4;
  const int lane = threadIdx.x;

  float acc[16];
#pragma unroll
  for (int j = 0; j < 16; ++j) acc[j] = 0.f;

  const __half* ap = a + kc * 392 * 1024 + bg * 64 + lane;
  const float* wp0 = w + kc * 392 * 256 + jg * 16;

#pragma unroll 4
  for (int k = 0; k < 392; ++k) {
    float av = __half2float(ap[k * 1024]);
    const float* wp = wp0 + k * 256;
#pragma unroll
    for (int j = 0; j < 16; ++j) acc[j] = fmaf(av, wp[j], acc[j]);
  }
#pragma unroll
  for (int j = 0; j < 16; ++j)
    part[(kc * 256 + jg * 16 + j) * 1024 + bg * 64 + lane] = acc[j];
}

// ---------------- fc1b: reduce 8 partials + bias + relu -> h_t[256][1024] ----------------
__global__ __launch_bounds__(256) void fc1b_k(const float* __restrict__ part,
                                              const float* __restrict__ bias,
                                              float* __restrict__ h) {
  int idx = blockIdx.x * 256 + threadIdx.x;   // j*1024 + b
  float s = bias[idx >> 10];
#pragma unroll
  for (int c = 0; c < 8; ++c) s += part[c * 262144 + idx];
  h[idx] = s > 0.f ? s : 0.f;
}

// ---------------- fc2 + softmax + dist/res (reads h_t[k][b]) ----------------
// NEW: fw2 staged in LDS once per block (52 KB); h reads are wave-uniform s_loads.
__global__ __launch_bounds__(256) void fc2_k(const float* __restrict__ h,     // [256][1024]
                                             const float* __restrict__ w,     // [256][51]
                                             const float* __restrict__ bias,
                                             const float* __restrict__ z,
                                             float* __restrict__ dist,        // [1024][6][51]
                                             float* __restrict__ res) {       // [1024][6]
  __shared__ float wl[256 * 51];
  const int tid = threadIdx.x;
#pragma unroll
  for (int i = tid; i < 256 * 51; i += 256) wl[i] = w[i];
  __syncthreads();

  const int j   = tid & 63;
  const int b   = blockIdx.x * 4 + RL(tid >> 6);
  const int jc = j < 51 ? j : 50;
  float acc = bias[jc];
#pragma unroll 8
  for (int k = 0; k < 256; ++k)
    acc = fmaf(h[k * 1024 + b], wl[k * 51 + jc], acc);
  float logit = (j < 51) ? acc : -1e30f;
  float m = logit;
#pragma unroll
  for (int o = 32; o > 0; o >>= 1) m = fmaxf(m, __shfl_xor(m, o, 64));
  float e = (j < 51) ? __expf(logit - m) : 0.f;
  float ssum = e;
#pragma unroll
  for (int o = 32; o > 0; o >>= 1) ssum += __shfl_xor(ssum, o, 64);
  float p = e / ssum;
  float zv = (j < 51) ? z[jc] : 0.f;
  float rz = p * zv;
#pragma unroll
  for (int o = 32; o > 0; o >>= 1) rz += __shfl_xor(rz, o, 64);
  if (j < 51) {
    float* db = dist + b * 6 * 51 + j;
#pragma unroll
    for (int n = 0; n < 6; ++n) db[n * 51] = p;
  }
  if (j < 6) res[b * 6 + j] = rz;
}

extern "C" void kernel_launch(void* const* d_in, const int* in_sizes, int n_in,
                              void* d_out, int out_size, void* d_ws, size_t ws_size,
                              hipStream_t stream) {
  const float* x   = (const float*)d_in[0];
  const float* cw1 = (const float*)d_in[1];
  const float* cb1 = (const float*)d_in[2];
  const float* cw2 = (const float*)d_in[3];
  const float* cb2 = (const float*)d_in[4];
  const float* cw3 = (const float*)d_in[5];
  const float* cb3 = (const float*)d_in[6];
  const float* fw1 = (const float*)d_in[7];
  const float* fb1 = (const float*)d_in[8];
  const float* fw2 = (const float*)d_in[9];
  const float* fb2 = (const float*)d_in[10];
  const float* z   = (const float*)d_in[11];

  float* ws = (float*)d_ws;
  // float-offsets (fp16 buffers occupy half):
  // c1h : [0, 6553600)          1024*12800 halfs
  // c1t : [6553600, 13107200)   12800*1024 halfs
  // c2t : [13107200, 15761408)  5184*1024 halfs
  // c3t : [15761408, 17367040)  3136*1024 halfs
  // part: [0, 2097152)          8*256*1024 fp32 (reuses dead c1h)
  // h_t : [2097152, 2359296)    256*1024 fp32
  __half* c1h = (__half*)ws;
  __half* c1t = (__half*)(ws + 6553600);
  __half* c2t = (__half*)(ws + 13107200);
  __half* c3t = (__half*)(ws + 15761408);
  float*  pw  = ws;
  float*  h_t = ws + 2097152;

  // Transposed conv weights in d_out scratch (77824 <= 319488); dist written last.
  float* wt2n = (float*)d_out;
  float* wt3n = (float*)d_out + 32768;
  float* wt1n = (float*)d_out + 69632;

  float* dist = (float*)d_out;
  float* res  = dist + 1024 * 6 * 51;

  wprep_k<<<144, 256, 0, stream>>>(cw1, cw2, cw3, wt1n, wt2n, wt3n);
  conv1_k<<<1024, 256, 0, stream>>>(x, wt1n, cb1, c1h);
  t1_k<<<dim3(200, 16), 256, 0, stream>>>(c1h, c1t);
  conv2_k<<<2304, 64, 0, stream>>>(c1t, wt2n, cb2, c2t);
  conv3_k<<<1792, 64, 0, stream>>>(c2t, wt3n, cb3, c3t);
  fc1a_k<<<2048, 64, 0, stream>>>(c3t, fw1, pw);
  fc1b_k<<<1024, 256, 0, stream>>>(pw, fb1, h_t);
  fc2_k<<<256, 256, 0, stream>>>(h_t, fw2, fb2, z, dist, res);
}

// Round 3
// 542.046 us; speedup vs baseline: 1.6126x; 1.6126x over previous
//
#include <hip/hip_runtime.h>
#include <hip/hip_fp16.h>

#define RL(x) __builtin_amdgcn_readfirstlane(x)

// ---------------- weight prep ----------------
// wt1n[(ic*8+ky)*256 + g*64 + j*8 + kx] = w1[(g*8+j)*256 + ic*64 + ky*8 + kx]   (8192)
// wt2n[((ic*4+ky)*8+ocg)*32 + o*4+kx]  = w2[(ocg*8+o)*512 + ic*16 + ky*4 + kx] (32768)
// wt3n[((ic*3+ky)*8+ocg)*24 + o*3+kx]  = w3[(ocg*8+o)*576 + ic*9  + ky*3 + kx] (36864)
__global__ __launch_bounds__(256) void wprep_k(const float* __restrict__ w1,
                                               const float* __restrict__ w2,
                                               const float* __restrict__ w3,
                                               float* __restrict__ wt1,
                                               float* __restrict__ wt2,
                                               float* __restrict__ wt3) {
  int i = blockIdx.x * 256 + threadIdx.x;
  if (i < 8192) {
    int kx = i & 7, j = (i >> 3) & 7, g = (i >> 6) & 3;
    int ky = (i >> 8) & 7, ic = i >> 11;
    wt1[i] = w1[(g * 8 + j) * 256 + ic * 64 + ky * 8 + kx];
  }
  if (i < 32768) {
    int o4 = i & 31, o = o4 >> 2, kx = o4 & 3;
    int r = i >> 5, ocg = r & 7, r2 = r >> 3, ky = r2 & 3, ic = r2 >> 2;
    wt2[i] = w2[(ocg * 8 + o) * 512 + ic * 16 + ky * 4 + kx];
  }
  if (i < 36864) {
    int o3 = i % 24, o = o3 / 3, kx = o3 - o * 3;
    int r = i / 24, ocg = r & 7, r2 = r >> 3, ky = r2 % 3, ic = r2 / 3;
    wt3[i] = w3[(ocg * 8 + o) * 576 + ic * 9 + ky * 3 + kx];
  }
}

// ---------------- conv1: x[1024,4,84,84] -> c1h[b][32*400] fp16, k=8, s=4 ----------------
// Pixels on lanes, SGPR weights, float4 A/B software pipeline (kept from R2).
__global__ __launch_bounds__(256, 2) void conv1_k(const float* __restrict__ x,
                                                  const float* __restrict__ wt,   // wt1n
                                                  const float* __restrict__ bias,
                                                  __half* __restrict__ out) {
  const int b    = blockIdx.x;
  const int tid  = threadIdx.x;
  const int lane = tid & 63;
  const int g    = RL(tid >> 6);

  int pv[7], ib[7];
#pragma unroll
  for (int s = 0; s < 7; ++s) {
    int p = lane + 64 * s;
    pv[s] = (p < 400);
    if (p > 399) p = 399;
    int py = p / 20, px = p - py * 20;
    ib[s] = py * 336 + px * 4;
  }

  float acc[7][8];
#pragma unroll
  for (int s = 0; s < 7; ++s)
#pragma unroll
    for (int j = 0; j < 8; ++j) acc[s][j] = 0.f;

  const float* xb = x + b * 28224;

#define C1_LD(av, cv, kk) do {                                                  \
    const float* rp = xb + ((kk) >> 3) * 7056 + ((kk) & 7) * 84;                \
    _Pragma("unroll") for (int s = 0; s < 7; ++s) {                             \
      av[s] = *(const float4*)(rp + ib[s]);                                     \
      cv[s] = *(const float4*)(rp + ib[s] + 4);                                 \
    }                                                                           \
  } while (0)

#define C1_CP(av, cv, kk) do {                                                  \
    const float* wp = wt + (kk) * 256 + g * 64;                                 \
    float wr[8][8];                                                             \
    _Pragma("unroll") for (int jj = 0; jj < 8; ++jj) {                          \
      float4 w0 = *(const float4*)(wp + jj * 8);                                \
      float4 w1 = *(const float4*)(wp + jj * 8 + 4);                            \
      wr[jj][0]=w0.x; wr[jj][1]=w0.y; wr[jj][2]=w0.z; wr[jj][3]=w0.w;           \
      wr[jj][4]=w1.x; wr[jj][5]=w1.y; wr[jj][6]=w1.z; wr[jj][7]=w1.w;           \
    }                                                                           \
    _Pragma("unroll") for (int s = 0; s < 7; ++s) {                             \
      float in8[8] = {av[s].x, av[s].y, av[s].z, av[s].w,                       \
                      cv[s].x, cv[s].y, cv[s].z, cv[s].w};                      \
      _Pragma("unroll") for (int jj = 0; jj < 8; ++jj)                          \
        _Pragma("unroll") for (int kx = 0; kx < 8; ++kx)                        \
          acc[s][jj] = fmaf(in8[kx], wr[jj][kx], acc[s][jj]);                   \
    }                                                                           \
  } while (0)

  float4 a0[7], c0[7], a1[7], c1v[7];
  C1_LD(a0, c0, 0);
#pragma unroll 1
  for (int k2 = 0; k2 < 16; ++k2) {
    const int k = 2 * k2;
    C1_LD(a1, c1v, k + 1);
    C1_CP(a0, c0, k);
    if (k2 < 15) C1_LD(a0, c0, k + 2);
    C1_CP(a1, c1v, k + 1);
  }
#undef C1_LD
#undef C1_CP

  const float inv256 = 1.0f / 256.0f;
#pragma unroll
  for (int j = 0; j < 8; ++j) {
    float bj = bias[g * 8 + j];
    __half* op = out + (b * 32 + g * 8 + j) * 400;
#pragma unroll
    for (int s = 0; s < 7; ++s) {
      if (pv[s]) {
        float v = acc[s][j] * inv256 + bj;
        op[lane + 64 * s] = __float2half(v > 0.f ? v : 0.f);
      }
    }
  }
}

// ---------------- t1: transpose c1h[1024][12800] -> c1t[12800][1024] (fp16) ----------------
__global__ __launch_bounds__(256) void t1_k(const __half* __restrict__ in,
                                            __half* __restrict__ out) {
  __shared__ __half t[64][65];
  const int kb = blockIdx.x * 64;   // 200 tiles
  const int bb = blockIdx.y * 64;   // 16 tiles
  const int lane = threadIdx.x & 63;
  const int ty   = threadIdx.x >> 6;
#pragma unroll
  for (int r = ty; r < 64; r += 4)
    t[r][lane] = in[(bb + r) * 12800 + kb + lane];
  __syncthreads();
#pragma unroll
  for (int r = ty; r < 64; r += 4)
    out[(kb + r) * 1024 + bb + lane] = t[lane][r];
}

// ---------------- conv2: c1t[12800][1024] -> c2t[5184][1024], k=4, s=2 (fp16 io) ----------
// Batch on lanes, 4 oc/wave. NEW: 128-thread block, 2 waves split the ic reduction
// (0..15 / 16..31), LDS reduce at the end. 2x waves/SIMD, traffic unchanged, no
// per-thread staging arrays (R2's spill is gone).
__global__ __launch_bounds__(128, 2) void conv2_k(const __half* __restrict__ in,
                                                  const float* __restrict__ wt,   // wt2n
                                                  const float* __restrict__ bias,
                                                  __half* __restrict__ out) {
  const int bid = blockIdx.x;            // 2304 = (bg*9 + opy)*16 + ocg
  const int ocg = bid & 15;
  const int r   = bid >> 4;
  const int opy = r % 9;
  const int bg  = r / 9;
  const int tid  = threadIdx.x;
  const int lane = tid & 63;
  const int wv   = RL(tid >> 6);

  float acc[4][9];
#pragma unroll
  for (int o = 0; o < 4; ++o)
#pragma unroll
    for (int ox = 0; ox < 9; ++ox) acc[o][ox] = 0.f;

  const __half* ib = in + bg * 64 + lane;
  const int ic0 = wv * 16;

#pragma unroll 1
  for (int ici = 0; ici < 16; ++ici) {
    const int ic = ic0 + ici;
#pragma unroll
    for (int ky = 0; ky < 4; ++ky) {
      const float* wp = wt + ((ic * 4 + ky) * 8 + (ocg >> 1)) * 32 + (ocg & 1) * 16;
      float wk[16];
#pragma unroll
      for (int q = 0; q < 16; ++q) wk[q] = wp[q];
      const __half* rp = ib + (ic * 400 + (2 * opy + ky) * 20) * 1024;
      float iv[20];
#pragma unroll
      for (int q = 0; q < 20; ++q) iv[q] = __half2float(rp[q * 1024]);
#pragma unroll
      for (int o = 0; o < 4; ++o)
#pragma unroll
        for (int ox = 0; ox < 9; ++ox)
#pragma unroll
          for (int kx = 0; kx < 4; ++kx)
            acc[o][ox] = fmaf(iv[2 * ox + kx], wk[o * 4 + kx], acc[o][ox]);
    }
  }

  __shared__ float red[4][9][64];
  if (wv == 1) {
#pragma unroll
    for (int o = 0; o < 4; ++o)
#pragma unroll
      for (int ox = 0; ox < 9; ++ox) red[o][ox][lane] = acc[o][ox];
  }
  __syncthreads();
  if (wv == 0) {
#pragma unroll
    for (int o = 0; o < 4; ++o) {
      const int oc = ocg * 4 + o;
      const float bj = bias[oc];
#pragma unroll
      for (int ox = 0; ox < 9; ++ox) {
        float v = acc[o][ox] + red[o][ox][lane] + bj;
        out[(oc * 81 + opy * 9 + ox) * 1024 + bg * 64 + lane] =
            __float2half(v > 0.f ? v : 0.f);
      }
    }
  }
}

// ---------------- conv3: c2t[5184][1024] -> c3t[3136][1024], k=3, s=1 (fp16 io) ----------
// Same 2-wave ic-split structure as conv2.
__global__ __launch_bounds__(128, 2) void conv3_k(const __half* __restrict__ in,
                                                  const float* __restrict__ wt,   // wt3n
                                                  const float* __restrict__ bias,
                                                  __half* __restrict__ out) {
  const int bid = blockIdx.x;            // 1792 = (bg*7 + opy)*16 + ocg
  const int ocg = bid & 15;
  const int r   = bid >> 4;
  const int opy = r % 7;
  const int bg  = r / 7;
  const int tid  = threadIdx.x;
  const int lane = tid & 63;
  const int wv   = RL(tid >> 6);

  float acc[4][7];
#pragma unroll
  for (int o = 0; o < 4; ++o)
#pragma unroll
    for (int ox = 0; ox < 7; ++ox) acc[o][ox] = 0.f;

  const __half* ib = in + bg * 64 + lane;
  const int ic0 = wv * 32;

#pragma unroll 1
  for (int ici = 0; ici < 32; ++ici) {
    const int ic = ic0 + ici;
#pragma unroll
    for (int ky = 0; ky < 3; ++ky) {
      const float* wp = wt + ((ic * 3 + ky) * 8 + (ocg >> 1)) * 24 + (ocg & 1) * 12;
      float wk[12];
#pragma unroll
      for (int q = 0; q < 12; ++q) wk[q] = wp[q];
      const __half* rp = ib + (ic * 81 + (opy + ky) * 9) * 1024;
      float iv[9];
#pragma unroll
      for (int q = 0; q < 9; ++q) iv[q] = __half2float(rp[q * 1024]);
#pragma unroll
      for (int o = 0; o < 4; ++o)
#pragma unroll
        for (int ox = 0; ox < 7; ++ox)
#pragma unroll
          for (int kx = 0; kx < 3; ++kx)
            acc[o][ox] = fmaf(iv[ox + kx], wk[o * 3 + kx], acc[o][ox]);
    }
  }

  __shared__ float red[4][7][64];
  if (wv == 1) {
#pragma unroll
    for (int o = 0; o < 4; ++o)
#pragma unroll
      for (int ox = 0; ox < 7; ++ox) red[o][ox][lane] = acc[o][ox];
  }
  __syncthreads();
  if (wv == 0) {
#pragma unroll
    for (int o = 0; o < 4; ++o) {
      const int oc = ocg * 4 + o;
      const float bj = bias[oc];
#pragma unroll
      for (int ox = 0; ox < 7; ++ox) {
        float v = acc[o][ox] + red[o][ox][lane] + bj;
        out[(oc * 49 + opy * 7 + ox) * 1024 + bg * 64 + lane] =
            __float2half(v > 0.f ? v : 0.f);
      }
    }
  }
}

// ---------------- fc1a: c3t[3136][1024] @ fw1[3136][256] -> part[16][256][1024] -----------
// NEW: kc split 8 -> 16 (k=196 each): 4096 waves, traffic unchanged.
__global__ __launch_bounds__(64, 2) void fc1a_k(const __half* __restrict__ a,
                                                const float* __restrict__ w,
                                                float* __restrict__ part) {
  const int bid = blockIdx.x;            // 4096 = (bg*16 + jg)*16 + kc
  const int kc = bid & 15;
  const int r  = bid >> 4;
  const int jg = r & 15;
  const int bg = r >> 4;
  const int lane = threadIdx.x;

  float acc[16];
#pragma unroll
  for (int j = 0; j < 16; ++j) acc[j] = 0.f;

  const __half* ap = a + kc * 196 * 1024 + bg * 64 + lane;
  const float* wp0 = w + kc * 196 * 256 + jg * 16;

#pragma unroll 4
  for (int k = 0; k < 196; ++k) {
    float av = __half2float(ap[k * 1024]);
    const float* wp = wp0 + k * 256;
#pragma unroll
    for (int j = 0; j < 16; ++j) acc[j] = fmaf(av, wp[j], acc[j]);
  }
#pragma unroll
  for (int j = 0; j < 16; ++j)
    part[(kc * 256 + jg * 16 + j) * 1024 + bg * 64 + lane] = acc[j];
}

// ---------------- fc1b: reduce 16 partials + bias + relu -> h_t[256][1024] ----------------
__global__ __launch_bounds__(256) void fc1b_k(const float* __restrict__ part,
                                              const float* __restrict__ bias,
                                              float* __restrict__ h) {
  int idx = blockIdx.x * 256 + threadIdx.x;   // j*1024 + b
  float s = bias[idx >> 10];
#pragma unroll
  for (int c = 0; c < 16; ++c) s += part[c * 262144 + idx];
  h[idx] = s > 0.f ? s : 0.f;
}

// ---------------- fc2 + softmax + dist/res (reads h_t[k][b]) ----------------
__global__ __launch_bounds__(256) void fc2_k(const float* __restrict__ h,     // [256][1024]
                                             const float* __restrict__ w,     // [256][51]
                                             const float* __restrict__ bias,
                                             const float* __restrict__ z,
                                             float* __restrict__ dist,        // [1024][6][51]
                                             float* __restrict__ res) {       // [1024][6]
  __shared__ float wl[256 * 51];
  const int tid = threadIdx.x;
#pragma unroll
  for (int i = tid; i < 256 * 51; i += 256) wl[i] = w[i];
  __syncthreads();

  const int j   = tid & 63;
  const int b   = blockIdx.x * 4 + RL(tid >> 6);
  const int jc = j < 51 ? j : 50;
  float acc = bias[jc];
#pragma unroll 8
  for (int k = 0; k < 256; ++k)
    acc = fmaf(h[k * 1024 + b], wl[k * 51 + jc], acc);
  float logit = (j < 51) ? acc : -1e30f;
  float m = logit;
#pragma unroll
  for (int o = 32; o > 0; o >>= 1) m = fmaxf(m, __shfl_xor(m, o, 64));
  float e = (j < 51) ? __expf(logit - m) : 0.f;
  float ssum = e;
#pragma unroll
  for (int o = 32; o > 0; o >>= 1) ssum += __shfl_xor(ssum, o, 64);
  float p = e / ssum;
  float zv = (j < 51) ? z[jc] : 0.f;
  float rz = p * zv;
#pragma unroll
  for (int o = 32; o > 0; o >>= 1) rz += __shfl_xor(rz, o, 64);
  if (j < 51) {
    float* db = dist + b * 6 * 51 + j;
#pragma unroll
    for (int n = 0; n < 6; ++n) db[n * 51] = p;
  }
  if (j < 6) res[b * 6 + j] = rz;
}

extern "C" void kernel_launch(void* const* d_in, const int* in_sizes, int n_in,
                              void* d_out, int out_size, void* d_ws, size_t ws_size,
                              hipStream_t stream) {
  const float* x   = (const float*)d_in[0];
  const float* cw1 = (const float*)d_in[1];
  const float* cb1 = (const float*)d_in[2];
  const float* cw2 = (const float*)d_in[3];
  const float* cb2 = (const float*)d_in[4];
  const float* cw3 = (const float*)d_in[5];
  const float* cb3 = (const float*)d_in[6];
  const float* fw1 = (const float*)d_in[7];
  const float* fb1 = (const float*)d_in[8];
  const float* fw2 = (const float*)d_in[9];
  const float* fb2 = (const float*)d_in[10];
  const float* z   = (const float*)d_in[11];

  float* ws = (float*)d_ws;
  // float-offsets (fp16 buffers occupy half):
  // c1h : [0, 6553600)          1024*12800 halfs
  // c1t : [6553600, 13107200)   12800*1024 halfs
  // c2t : [13107200, 15761408)  5184*1024 halfs
  // c3t : [15761408, 17367040)  3136*1024 halfs
  // part: [0, 4194304)          16*256*1024 fp32 (reuses dead c1h)
  // h_t : [4194304, 4456448)    256*1024 fp32
  __half* c1h = (__half*)ws;
  __half* c1t = (__half*)(ws + 6553600);
  __half* c2t = (__half*)(ws + 13107200);
  __half* c3t = (__half*)(ws + 15761408);
  float*  pw  = ws;
  float*  h_t = ws + 4194304;

  // Transposed conv weights in d_out scratch (77824 <= 319488); dist written last.
  float* wt2n = (float*)d_out;
  float* wt3n = (float*)d_out + 32768;
  float* wt1n = (float*)d_out + 69632;

  float* dist = (float*)d_out;
  float* res  = dist + 1024 * 6 * 51;

  wprep_k<<<144, 256, 0, stream>>>(cw1, cw2, cw3, wt1n, wt2n, wt3n);
  conv1_k<<<1024, 256, 0, stream>>>(x, wt1n, cb1, c1h);
  t1_k<<<dim3(200, 16), 256, 0, stream>>>(c1h, c1t);
  conv2_k<<<2304, 128, 0, stream>>>(c1t, wt2n, cb2, c2t);
  conv3_k<<<1792, 128, 0, stream>>>(c2t, wt3n, cb3, c3t);
  fc1a_k<<<4096, 64, 0, stream>>>(c3t, fw1, pw);
  fc1b_k<<<1024, 256, 0, stream>>>(pw, fb1, h_t);
  fc2_k<<<256, 256, 0, stream>>>(h_t, fw2, fb2, z, dist, res);
}

// Round 4
// 478.369 us; speedup vs baseline: 1.8272x; 1.1331x over previous
//
#include <hip/hip_runtime.h>
#include <hip/hip_fp16.h>

#define RL(x) __builtin_amdgcn_readfirstlane(x)

// ---------------- weight prep ----------------
// wt1n[(ic*8+ky)*256 + g*64 + j*8 + kx] = w1[(g*8+j)*256 + ic*64 + ky*8 + kx]   (8192)
// wt2n[((ic*4+ky)*8+ocg)*32 + o*4+kx]  = w2[(ocg*8+o)*512 + ic*16 + ky*4 + kx] (32768)
// wt3n[((ic*3+ky)*8+ocg)*24 + o*3+kx]  = w3[(ocg*8+o)*576 + ic*9  + ky*3 + kx] (36864)
__global__ __launch_bounds__(256) void wprep_k(const float* __restrict__ w1,
                                               const float* __restrict__ w2,
                                               const float* __restrict__ w3,
                                               float* __restrict__ wt1,
                                               float* __restrict__ wt2,
                                               float* __restrict__ wt3) {
  int i = blockIdx.x * 256 + threadIdx.x;
  if (i < 8192) {
    int kx = i & 7, j = (i >> 3) & 7, g = (i >> 6) & 3;
    int ky = (i >> 8) & 7, ic = i >> 11;
    wt1[i] = w1[(g * 8 + j) * 256 + ic * 64 + ky * 8 + kx];
  }
  if (i < 32768) {
    int o4 = i & 31, o = o4 >> 2, kx = o4 & 3;
    int r = i >> 5, ocg = r & 7, r2 = r >> 3, ky = r2 & 3, ic = r2 >> 2;
    wt2[i] = w2[(ocg * 8 + o) * 512 + ic * 16 + ky * 4 + kx];
  }
  if (i < 36864) {
    int o3 = i % 24, o = o3 / 3, kx = o3 - o * 3;
    int r = i / 24, ocg = r & 7, r2 = r >> 3, ky = r2 % 3, ic = r2 / 3;
    wt3[i] = w3[(ocg * 8 + o) * 576 + ic * 9 + ky * 3 + kx];
  }
}

// ---------------- conv1: x[1024,4,84,84] -> c1h[b][32*400] fp16, k=8, s=4 ----------------
// NEW: input ic-plane staged in LDS (28224 B); per-phase reads are ds_read_b128 on
// the LDS pipe instead of 14 KB/phase of redundant vector-path global loads.
// 4 blocks/CU (112 KB LDS); ic order staggered so resident blocks don't barrier together.
__global__ __launch_bounds__(256, 4) void conv1_k(const float* __restrict__ x,
                                                  const float* __restrict__ wt,   // wt1n
                                                  const float* __restrict__ bias,
                                                  __half* __restrict__ out) {
  __shared__ float plane[7056];          // one 84x84 fp32 ic-plane
  const int b    = blockIdx.x;
  const int tid  = threadIdx.x;
  const int lane = tid & 63;
  const int g    = RL(tid >> 6);

  int pv[7], ib[7];
#pragma unroll
  for (int s = 0; s < 7; ++s) {
    int p = lane + 64 * s;
    pv[s] = (p < 400);
    if (p > 399) p = 399;
    int py = p / 20, px = p - py * 20;
    ib[s] = py * 336 + px * 4;           // float index into an 84x84 plane (row py*4)
  }

  float acc[7][8];
#pragma unroll
  for (int s = 0; s < 7; ++s)
#pragma unroll
    for (int j = 0; j < 8; ++j) acc[s][j] = 0.f;

  const float* xb = x + b * 28224;

#pragma unroll 1
  for (int ici = 0; ici < 4; ++ici) {
    const int ic = (ici + (b >> 8)) & 3;   // stagger same-CU blocks (spaced ~256 apart)
    if (ici) __syncthreads();              // prior reads done before overwrite
    // ---- stage ic plane: 1764 float4 = 28224 B ----
    const float* xp = xb + ic * 7056;
#pragma unroll
    for (int i = 0; i < 7; ++i) {
      int idx = tid + i * 256;
      if (idx < 1764) {
        float4 v = *(const float4*)(xp + idx * 4);
        *(float4*)&plane[idx * 4] = v;
      }
    }
    __syncthreads();

#pragma unroll 1
    for (int ky = 0; ky < 8; ++ky) {
      const float* wp = wt + (ic * 8 + ky) * 256 + g * 64;   // uniform -> s_load
      float wr[8][8];
#pragma unroll
      for (int j = 0; j < 8; ++j) {
        float4 w0 = *(const float4*)(wp + j * 8);
        float4 w1 = *(const float4*)(wp + j * 8 + 4);
        wr[j][0]=w0.x; wr[j][1]=w0.y; wr[j][2]=w0.z; wr[j][3]=w0.w;
        wr[j][4]=w1.x; wr[j][5]=w1.y; wr[j][6]=w1.z; wr[j][7]=w1.w;
      }
      const float* rp = plane + ky * 84;   // LDS reads from here on
#pragma unroll
      for (int s = 0; s < 7; ++s) {
        float4 a = *(const float4*)(rp + ib[s]);
        float4 c = *(const float4*)(rp + ib[s] + 4);
        float in8[8] = {a.x, a.y, a.z, a.w, c.x, c.y, c.z, c.w};
#pragma unroll
        for (int j = 0; j < 8; ++j)
#pragma unroll
          for (int kx = 0; kx < 8; ++kx)
            acc[s][j] = fmaf(in8[kx], wr[j][kx], acc[s][j]);
      }
    }
  }

  const float inv256 = 1.0f / 256.0f;
#pragma unroll
  for (int j = 0; j < 8; ++j) {
    float bj = bias[g * 8 + j];
    __half* op = out + (b * 32 + g * 8 + j) * 400;
#pragma unroll
    for (int s = 0; s < 7; ++s) {
      if (pv[s]) {
        float v = acc[s][j] * inv256 + bj;
        op[lane + 64 * s] = __float2half(v > 0.f ? v : 0.f);
      }
    }
  }
}

// ---------------- t1: transpose c1h[1024][12800] -> c1t[12800][1024] (fp16) ----------------
__global__ __launch_bounds__(256) void t1_k(const __half* __restrict__ in,
                                            __half* __restrict__ out) {
  __shared__ __half t[64][65];
  const int kb = blockIdx.x * 64;   // 200 tiles
  const int bb = blockIdx.y * 64;   // 16 tiles
  const int lane = threadIdx.x & 63;
  const int ty   = threadIdx.x >> 6;
#pragma unroll
  for (int r = ty; r < 64; r += 4)
    t[r][lane] = in[(bb + r) * 12800 + kb + lane];
  __syncthreads();
#pragma unroll
  for (int r = ty; r < 64; r += 4)
    out[(kb + r) * 1024 + bb + lane] = t[lane][r];
}

// ---------------- conv2: c1t[12800][1024] -> c2t[5184][1024], k=4, s=2 (fp16 io) ----------
// 128-thread block, 2 waves split the ic reduction, LDS reduce at the end.
__global__ __launch_bounds__(128, 2) void conv2_k(const __half* __restrict__ in,
                                                  const float* __restrict__ wt,   // wt2n
                                                  const float* __restrict__ bias,
                                                  __half* __restrict__ out) {
  const int bid = blockIdx.x;            // 2304 = (bg*9 + opy)*16 + ocg
  const int ocg = bid & 15;
  const int r   = bid >> 4;
  const int opy = r % 9;
  const int bg  = r / 9;
  const int tid  = threadIdx.x;
  const int lane = tid & 63;
  const int wv   = RL(tid >> 6);

  float acc[4][9];
#pragma unroll
  for (int o = 0; o < 4; ++o)
#pragma unroll
    for (int ox = 0; ox < 9; ++ox) acc[o][ox] = 0.f;

  const __half* ib = in + bg * 64 + lane;
  const int ic0 = wv * 16;

#pragma unroll 1
  for (int ici = 0; ici < 16; ++ici) {
    const int ic = ic0 + ici;
#pragma unroll
    for (int ky = 0; ky < 4; ++ky) {
      const float* wp = wt + ((ic * 4 + ky) * 8 + (ocg >> 1)) * 32 + (ocg & 1) * 16;
      float wk[16];
#pragma unroll
      for (int q = 0; q < 16; ++q) wk[q] = wp[q];
      const __half* rp = ib + (ic * 400 + (2 * opy + ky) * 20) * 1024;
      float iv[20];
#pragma unroll
      for (int q = 0; q < 20; ++q) iv[q] = __half2float(rp[q * 1024]);
#pragma unroll
      for (int o = 0; o < 4; ++o)
#pragma unroll
        for (int ox = 0; ox < 9; ++ox)
#pragma unroll
          for (int kx = 0; kx < 4; ++kx)
            acc[o][ox] = fmaf(iv[2 * ox + kx], wk[o * 4 + kx], acc[o][ox]);
    }
  }

  __shared__ float red[4][9][64];
  if (wv == 1) {
#pragma unroll
    for (int o = 0; o < 4; ++o)
#pragma unroll
      for (int ox = 0; ox < 9; ++ox) red[o][ox][lane] = acc[o][ox];
  }
  __syncthreads();
  if (wv == 0) {
#pragma unroll
    for (int o = 0; o < 4; ++o) {
      const int oc = ocg * 4 + o;
      const float bj = bias[oc];
#pragma unroll
      for (int ox = 0; ox < 9; ++ox) {
        float v = acc[o][ox] + red[o][ox][lane] + bj;
        out[(oc * 81 + opy * 9 + ox) * 1024 + bg * 64 + lane] =
            __float2half(v > 0.f ? v : 0.f);
      }
    }
  }
}

// ---------------- conv3: c2t[5184][1024] -> c3t[3136][1024], k=3, s=1 (fp16 io) ----------
__global__ __launch_bounds__(128, 2) void conv3_k(const __half* __restrict__ in,
                                                  const float* __restrict__ wt,   // wt3n
                                                  const float* __restrict__ bias,
                                                  __half* __restrict__ out) {
  const int bid = blockIdx.x;            // 1792 = (bg*7 + opy)*16 + ocg
  const int ocg = bid & 15;
  const int r   = bid >> 4;
  const int opy = r % 7;
  const int bg  = r / 7;
  const int tid  = threadIdx.x;
  const int lane = tid & 63;
  const int wv   = RL(tid >> 6);

  float acc[4][7];
#pragma unroll
  for (int o = 0; o < 4; ++o)
#pragma unroll
    for (int ox = 0; ox < 7; ++ox) acc[o][ox] = 0.f;

  const __half* ib = in + bg * 64 + lane;
  const int ic0 = wv * 32;

#pragma unroll 1
  for (int ici = 0; ici < 32; ++ici) {
    const int ic = ic0 + ici;
#pragma unroll
    for (int ky = 0; ky < 3; ++ky) {
      const float* wp = wt + ((ic * 3 + ky) * 8 + (ocg >> 1)) * 24 + (ocg & 1) * 12;
      float wk[12];
#pragma unroll
      for (int q = 0; q < 12; ++q) wk[q] = wp[q];
      const __half* rp = ib + (ic * 81 + (opy + ky) * 9) * 1024;
      float iv[9];
#pragma unroll
      for (int q = 0; q < 9; ++q) iv[q] = __half2float(rp[q * 1024]);
#pragma unroll
      for (int o = 0; o < 4; ++o)
#pragma unroll
        for (int ox = 0; ox < 7; ++ox)
#pragma unroll
          for (int kx = 0; kx < 3; ++kx)
            acc[o][ox] = fmaf(iv[ox + kx], wk[o * 3 + kx], acc[o][ox]);
    }
  }

  __shared__ float red[4][7][64];
  if (wv == 1) {
#pragma unroll
    for (int o = 0; o < 4; ++o)
#pragma unroll
      for (int ox = 0; ox < 7; ++ox) red[o][ox][lane] = acc[o][ox];
  }
  __syncthreads();
  if (wv == 0) {
#pragma unroll
    for (int o = 0; o < 4; ++o) {
      const int oc = ocg * 4 + o;
      const float bj = bias[oc];
#pragma unroll
      for (int ox = 0; ox < 7; ++ox) {
        float v = acc[o][ox] + red[o][ox][lane] + bj;
        out[(oc * 49 + opy * 7 + ox) * 1024 + bg * 64 + lane] =
            __float2half(v > 0.f ? v : 0.f);
      }
    }
  }
}

// ---------------- fc1a: c3t[3136][1024] @ fw1[3136][256] -> part[16][256][1024] -----------
__global__ __launch_bounds__(64, 2) void fc1a_k(const __half* __restrict__ a,
                                                const float* __restrict__ w,
                                                float* __restrict__ part) {
  const int bid = blockIdx.x;            // 4096 = (bg*16 + jg)*16 + kc
  const int kc = bid & 15;
  const int r  = bid >> 4;
  const int jg = r & 15;
  const int bg = r >> 4;
  const int lane = threadIdx.x;

  float acc[16];
#pragma unroll
  for (int j = 0; j < 16; ++j) acc[j] = 0.f;

  const __half* ap = a + kc * 196 * 1024 + bg * 64 + lane;
  const float* wp0 = w + kc * 196 * 256 + jg * 16;

#pragma unroll 4
  for (int k = 0; k < 196; ++k) {
    float av = __half2float(ap[k * 1024]);
    const float* wp = wp0 + k * 256;
#pragma unroll
    for (int j = 0; j < 16; ++j) acc[j] = fmaf(av, wp[j], acc[j]);
  }
#pragma unroll
  for (int j = 0; j < 16; ++j)
    part[(kc * 256 + jg * 16 + j) * 1024 + bg * 64 + lane] = acc[j];
}

// ---------------- fc1b: reduce 16 partials + bias + relu -> h_t[256][1024] ----------------
__global__ __launch_bounds__(256) void fc1b_k(const float* __restrict__ part,
                                              const float* __restrict__ bias,
                                              float* __restrict__ h) {
  int idx = blockIdx.x * 256 + threadIdx.x;   // j*1024 + b
  float s = bias[idx >> 10];
#pragma unroll
  for (int c = 0; c < 16; ++c) s += part[c * 262144 + idx];
  h[idx] = s > 0.f ? s : 0.f;
}

// ---------------- fc2 + softmax + dist/res (reads h_t[k][b]) ----------------
__global__ __launch_bounds__(256) void fc2_k(const float* __restrict__ h,     // [256][1024]
                                             const float* __restrict__ w,     // [256][51]
                                             const float* __restrict__ bias,
                                             const float* __restrict__ z,
                                             float* __restrict__ dist,        // [1024][6][51]
                                             float* __restrict__ res) {       // [1024][6]
  __shared__ float wl[256 * 51];
  const int tid = threadIdx.x;
#pragma unroll
  for (int i = tid; i < 256 * 51; i += 256) wl[i] = w[i];
  __syncthreads();

  const int j   = tid & 63;
  const int b   = blockIdx.x * 4 + RL(tid >> 6);
  const int jc = j < 51 ? j : 50;
  float acc = bias[jc];
#pragma unroll 8
  for (int k = 0; k < 256; ++k)
    acc = fmaf(h[k * 1024 + b], wl[k * 51 + jc], acc);
  float logit = (j < 51) ? acc : -1e30f;
  float m = logit;
#pragma unroll
  for (int o = 32; o > 0; o >>= 1) m = fmaxf(m, __shfl_xor(m, o, 64));
  float e = (j < 51) ? __expf(logit - m) : 0.f;
  float ssum = e;
#pragma unroll
  for (int o = 32; o > 0; o >>= 1) ssum += __shfl_xor(ssum, o, 64);
  float p = e / ssum;
  float zv = (j < 51) ? z[jc] : 0.f;
  float rz = p * zv;
#pragma unroll
  for (int o = 32; o > 0; o >>= 1) rz += __shfl_xor(rz, o, 64);
  if (j < 51) {
    float* db = dist + b * 6 * 51 + j;
#pragma unroll
    for (int n = 0; n < 6; ++n) db[n * 51] = p;
  }
  if (j < 6) res[b * 6 + j] = rz;
}

extern "C" void kernel_launch(void* const* d_in, const int* in_sizes, int n_in,
                              void* d_out, int out_size, void* d_ws, size_t ws_size,
                              hipStream_t stream) {
  const float* x   = (const float*)d_in[0];
  const float* cw1 = (const float*)d_in[1];
  const float* cb1 = (const float*)d_in[2];
  const float* cw2 = (const float*)d_in[3];
  const float* cb2 = (const float*)d_in[4];
  const float* cw3 = (const float*)d_in[5];
  const float* cb3 = (const float*)d_in[6];
  const float* fw1 = (const float*)d_in[7];
  const float* fb1 = (const float*)d_in[8];
  const float* fw2 = (const float*)d_in[9];
  const float* fb2 = (const float*)d_in[10];
  const float* z   = (const float*)d_in[11];

  float* ws = (float*)d_ws;
  // float-offsets (fp16 buffers occupy half):
  // c1h : [0, 6553600)          1024*12800 halfs
  // c1t : [6553600, 13107200)   12800*1024 halfs
  // c2t : [13107200, 15761408)  5184*1024 halfs
  // c3t : [15761408, 17367040)  3136*1024 halfs
  // part: [0, 4194304)          16*256*1024 fp32 (reuses dead c1h)
  // h_t : [4194304, 4456448)    256*1024 fp32
  __half* c1h = (__half*)ws;
  __half* c1t = (__half*)(ws + 6553600);
  __half* c2t = (__half*)(ws + 13107200);
  __half* c3t = (__half*)(ws + 15761408);
  float*  pw  = ws;
  float*  h_t = ws + 4194304;

  // Transposed conv weights in d_out scratch (77824 <= 319488); dist written last.
  float* wt2n = (float*)d_out;
  float* wt3n = (float*)d_out + 32768;
  float* wt1n = (float*)d_out + 69632;

  float* dist = (float*)d_out;
  float* res  = dist + 1024 * 6 * 51;

  wprep_k<<<144, 256, 0, stream>>>(cw1, cw2, cw3, wt1n, wt2n, wt3n);
  conv1_k<<<1024, 256, 0, stream>>>(x, wt1n, cb1, c1h);
  t1_k<<<dim3(200, 16), 256, 0, stream>>>(c1h, c1t);
  conv2_k<<<2304, 128, 0, stream>>>(c1t, wt2n, cb2, c2t);
  conv3_k<<<1792, 128, 0, stream>>>(c2t, wt3n, cb3, c3t);
  fc1a_k<<<4096, 64, 0, stream>>>(c3t, fw1, pw);
  fc1b_k<<<1024, 256, 0, stream>>>(pw, fb1, h_t);
  fc2_k<<<256, 256, 0, stream>>>(h_t, fw2, fb2, z, dist, res);
}

// Round 5
// 473.472 us; speedup vs baseline: 1.8461x; 1.0103x over previous
//
#include <hip/hip_runtime.h>
#include <hip/hip_fp16.h>

#define RL(x) __builtin_amdgcn_readfirstlane(x)

// ---------------- weight prep ----------------
// wt1n[(ic*8+ky)*256 + g*64 + j*8 + kx] = w1[(g*8+j)*256 + ic*64 + ky*8 + kx]   (8192)
// wt2n[((ic*4+ky)*8+ocg)*32 + o*4+kx]  = w2[(ocg*8+o)*512 + ic*16 + ky*4 + kx] (32768)
// wt3n[((ic*3+ky)*8+ocg)*24 + o*3+kx]  = w3[(ocg*8+o)*576 + ic*9  + ky*3 + kx] (36864)
__global__ __launch_bounds__(256) void wprep_k(const float* __restrict__ w1,
                                               const float* __restrict__ w2,
                                               const float* __restrict__ w3,
                                               float* __restrict__ wt1,
                                               float* __restrict__ wt2,
                                               float* __restrict__ wt3) {
  int i = blockIdx.x * 256 + threadIdx.x;
  if (i < 8192) {
    int kx = i & 7, j = (i >> 3) & 7, g = (i >> 6) & 3;
    int ky = (i >> 8) & 7, ic = i >> 11;
    wt1[i] = w1[(g * 8 + j) * 256 + ic * 64 + ky * 8 + kx];
  }
  if (i < 32768) {
    int o4 = i & 31, o = o4 >> 2, kx = o4 & 3;
    int r = i >> 5, ocg = r & 7, r2 = r >> 3, ky = r2 & 3, ic = r2 >> 2;
    wt2[i] = w2[(ocg * 8 + o) * 512 + ic * 16 + ky * 4 + kx];
  }
  if (i < 36864) {
    int o3 = i % 24, o = o3 / 3, kx = o3 - o * 3;
    int r = i / 24, ocg = r & 7, r2 = r >> 3, ky = r2 % 3, ic = r2 / 3;
    wt3[i] = w3[(ocg * 8 + o) * 576 + ic * 9 + ky * 3 + kx];
  }
}

// ---------------- conv1: x[1024,4,84,84] -> c1h[b][32*400] fp16, k=8, s=4 ----------------
// Input ic-plane staged in LDS (28224 B); per-phase reads on the LDS pipe.
__global__ __launch_bounds__(256, 4) void conv1_k(const float* __restrict__ x,
                                                  const float* __restrict__ wt,   // wt1n
                                                  const float* __restrict__ bias,
                                                  __half* __restrict__ out) {
  __shared__ float plane[7056];          // one 84x84 fp32 ic-plane
  const int b    = blockIdx.x;
  const int tid  = threadIdx.x;
  const int lane = tid & 63;
  const int g    = RL(tid >> 6);

  int pv[7], ib[7];
#pragma unroll
  for (int s = 0; s < 7; ++s) {
    int p = lane + 64 * s;
    pv[s] = (p < 400);
    if (p > 399) p = 399;
    int py = p / 20, px = p - py * 20;
    ib[s] = py * 336 + px * 4;           // float index into an 84x84 plane (row py*4)
  }

  float acc[7][8];
#pragma unroll
  for (int s = 0; s < 7; ++s)
#pragma unroll
    for (int j = 0; j < 8; ++j) acc[s][j] = 0.f;

  const float* xb = x + b * 28224;

#pragma unroll 1
  for (int ici = 0; ici < 4; ++ici) {
    const int ic = (ici + (b >> 8)) & 3;   // stagger same-CU blocks
    if (ici) __syncthreads();              // prior reads done before overwrite
    const float* xp = xb + ic * 7056;
#pragma unroll
    for (int i = 0; i < 7; ++i) {
      int idx = tid + i * 256;
      if (idx < 1764) {
        float4 v = *(const float4*)(xp + idx * 4);
        *(float4*)&plane[idx * 4] = v;
      }
    }
    __syncthreads();

#pragma unroll 1
    for (int ky = 0; ky < 8; ++ky) {
      const float* wp = wt + (ic * 8 + ky) * 256 + g * 64;   // uniform -> s_load
      float wr[8][8];
#pragma unroll
      for (int j = 0; j < 8; ++j) {
        float4 w0 = *(const float4*)(wp + j * 8);
        float4 w1 = *(const float4*)(wp + j * 8 + 4);
        wr[j][0]=w0.x; wr[j][1]=w0.y; wr[j][2]=w0.z; wr[j][3]=w0.w;
        wr[j][4]=w1.x; wr[j][5]=w1.y; wr[j][6]=w1.z; wr[j][7]=w1.w;
      }
      const float* rp = plane + ky * 84;   // LDS reads
#pragma unroll
      for (int s = 0; s < 7; ++s) {
        float4 a = *(const float4*)(rp + ib[s]);
        float4 c = *(const float4*)(rp + ib[s] + 4);
        float in8[8] = {a.x, a.y, a.z, a.w, c.x, c.y, c.z, c.w};
#pragma unroll
        for (int j = 0; j < 8; ++j)
#pragma unroll
          for (int kx = 0; kx < 8; ++kx)
            acc[s][j] = fmaf(in8[kx], wr[j][kx], acc[s][j]);
      }
    }
  }

  const float inv256 = 1.0f / 256.0f;
#pragma unroll
  for (int j = 0; j < 8; ++j) {
    float bj = bias[g * 8 + j];
    __half* op = out + (b * 32 + g * 8 + j) * 400;
#pragma unroll
    for (int s = 0; s < 7; ++s) {
      if (pv[s]) {
        float v = acc[s][j] * inv256 + bj;
        op[lane + 64 * s] = __float2half(v > 0.f ? v : 0.f);
      }
    }
  }
}

// ---------------- t1: transpose c1h[1024][12800] -> c1t[12800][1024] (fp16) ----------------
__global__ __launch_bounds__(256) void t1_k(const __half* __restrict__ in,
                                            __half* __restrict__ out) {
  __shared__ __half t[64][65];
  const int kb = blockIdx.x * 64;   // 200 tiles
  const int bb = blockIdx.y * 64;   // 16 tiles
  const int lane = threadIdx.x & 63;
  const int ty   = threadIdx.x >> 6;
#pragma unroll
  for (int r = ty; r < 64; r += 4)
    t[r][lane] = in[(bb + r) * 12800 + kb + lane];
  __syncthreads();
#pragma unroll
  for (int r = ty; r < 64; r += 4)
    out[(kb + r) * 1024 + bb + lane] = t[lane][r];
}

// ---------------- conv2: c1t[12800][1024] -> c2t[5184][1024], k=4, s=2 (fp16 io) ----------
// 128-thread block, 2-wave ic split. NEW: XCD-colocating block remap — the 16
// ocg-blocks sharing one (bg,opy) input slab get identical bid%8 (same XCD L2)
// and adjacent dispatch slots: bid = (grp&7) + 8*ocg + 128*(grp>>3), grp=bg*9+opy.
__global__ __launch_bounds__(128, 2) void conv2_k(const __half* __restrict__ in,
                                                  const float* __restrict__ wt,   // wt2n
                                                  const float* __restrict__ bias,
                                                  __half* __restrict__ out) {
  const int bid = blockIdx.x;            // 2304 = 128*(grp>>3) + 8*ocg + (grp&7)
  const int ocg = (bid >> 3) & 15;
  const int grp = ((bid >> 7) << 3) | (bid & 7);
  const int opy = grp % 9;
  const int bg  = grp / 9;
  const int tid  = threadIdx.x;
  const int lane = tid & 63;
  const int wv   = RL(tid >> 6);

  float acc[4][9];
#pragma unroll
  for (int o = 0; o < 4; ++o)
#pragma unroll
    for (int ox = 0; ox < 9; ++ox) acc[o][ox] = 0.f;

  const __half* ib = in + bg * 64 + lane;
  const int ic0 = wv * 16;

#pragma unroll 1
  for (int ici = 0; ici < 16; ++ici) {
    const int ic = ic0 + ici;
#pragma unroll
    for (int ky = 0; ky < 4; ++ky) {
      const float* wp = wt + ((ic * 4 + ky) * 8 + (ocg >> 1)) * 32 + (ocg & 1) * 16;
      float wk[16];
#pragma unroll
      for (int q = 0; q < 16; ++q) wk[q] = wp[q];
      const __half* rp = ib + (ic * 400 + (2 * opy + ky) * 20) * 1024;
      float iv[20];
#pragma unroll
      for (int q = 0; q < 20; ++q) iv[q] = __half2float(rp[q * 1024]);
#pragma unroll
      for (int o = 0; o < 4; ++o)
#pragma unroll
        for (int ox = 0; ox < 9; ++ox)
#pragma unroll
          for (int kx = 0; kx < 4; ++kx)
            acc[o][ox] = fmaf(iv[2 * ox + kx], wk[o * 4 + kx], acc[o][ox]);
    }
  }

  __shared__ float red[4][9][64];
  if (wv == 1) {
#pragma unroll
    for (int o = 0; o < 4; ++o)
#pragma unroll
      for (int ox = 0; ox < 9; ++ox) red[o][ox][lane] = acc[o][ox];
  }
  __syncthreads();
  if (wv == 0) {
#pragma unroll
    for (int o = 0; o < 4; ++o) {
      const int oc = ocg * 4 + o;
      const float bj = bias[oc];
#pragma unroll
      for (int ox = 0; ox < 9; ++ox) {
        float v = acc[o][ox] + red[o][ox][lane] + bj;
        out[(oc * 81 + opy * 9 + ox) * 1024 + bg * 64 + lane] =
            __float2half(v > 0.f ? v : 0.f);
      }
    }
  }
}

// ---------------- conv3: c2t[5184][1024] -> c3t[3136][1024], k=3, s=1 (fp16 io) ----------
// Same 2-wave ic-split + XCD-colocating remap (grp = bg*7+opy, 112 = 14*8).
__global__ __launch_bounds__(128, 2) void conv3_k(const __half* __restrict__ in,
                                                  const float* __restrict__ wt,   // wt3n
                                                  const float* __restrict__ bias,
                                                  __half* __restrict__ out) {
  const int bid = blockIdx.x;            // 1792 = 128*(grp>>3) + 8*ocg + (grp&7)
  const int ocg = (bid >> 3) & 15;
  const int grp = ((bid >> 7) << 3) | (bid & 7);
  const int opy = grp % 7;
  const int bg  = grp / 7;
  const int tid  = threadIdx.x;
  const int lane = tid & 63;
  const int wv   = RL(tid >> 6);

  float acc[4][7];
#pragma unroll
  for (int o = 0; o < 4; ++o)
#pragma unroll
    for (int ox = 0; ox < 7; ++ox) acc[o][ox] = 0.f;

  const __half* ib = in + bg * 64 + lane;
  const int ic0 = wv * 32;

#pragma unroll 1
  for (int ici = 0; ici < 32; ++ici) {
    const int ic = ic0 + ici;
#pragma unroll
    for (int ky = 0; ky < 3; ++ky) {
      const float* wp = wt + ((ic * 3 + ky) * 8 + (ocg >> 1)) * 24 + (ocg & 1) * 12;
      float wk[12];
#pragma unroll
      for (int q = 0; q < 12; ++q) wk[q] = wp[q];
      const __half* rp = ib + (ic * 81 + (opy + ky) * 9) * 1024;
      float iv[9];
#pragma unroll
      for (int q = 0; q < 9; ++q) iv[q] = __half2float(rp[q * 1024]);
#pragma unroll
      for (int o = 0; o < 4; ++o)
#pragma unroll
        for (int ox = 0; ox < 7; ++ox)
#pragma unroll
          for (int kx = 0; kx < 3; ++kx)
            acc[o][ox] = fmaf(iv[ox + kx], wk[o * 3 + kx], acc[o][ox]);
    }
  }

  __shared__ float red[4][7][64];
  if (wv == 1) {
#pragma unroll
    for (int o = 0; o < 4; ++o)
#pragma unroll
      for (int ox = 0; ox < 7; ++ox) red[o][ox][lane] = acc[o][ox];
  }
  __syncthreads();
  if (wv == 0) {
#pragma unroll
    for (int o = 0; o < 4; ++o) {
      const int oc = ocg * 4 + o;
      const float bj = bias[oc];
#pragma unroll
      for (int ox = 0; ox < 7; ++ox) {
        float v = acc[o][ox] + red[o][ox][lane] + bj;
        out[(oc * 49 + opy * 7 + ox) * 1024 + bg * 64 + lane] =
            __float2half(v > 0.f ? v : 0.f);
      }
    }
  }
}

// ---------------- fc1a: c3t[3136][1024] @ fw1[3136][256] -> part[16][256][1024] -----------
// XCD-colocating remap: 16 jg-blocks sharing one (bg,kc) a-slab on the same XCD
// (grp = bg*16+kc, 256 = 32*8).
__global__ __launch_bounds__(64, 2) void fc1a_k(const __half* __restrict__ a,
                                                const float* __restrict__ w,
                                                float* __restrict__ part) {
  const int bid = blockIdx.x;            // 4096 = 128*(grp>>3) + 8*jg + (grp&7)
  const int jg  = (bid >> 3) & 15;
  const int grp = ((bid >> 7) << 3) | (bid & 7);
  const int kc  = grp & 15;
  const int bg  = grp >> 4;
  const int lane = threadIdx.x;

  float acc[16];
#pragma unroll
  for (int j = 0; j < 16; ++j) acc[j] = 0.f;

  const __half* ap = a + kc * 196 * 1024 + bg * 64 + lane;
  const float* wp0 = w + kc * 196 * 256 + jg * 16;

#pragma unroll 4
  for (int k = 0; k < 196; ++k) {
    float av = __half2float(ap[k * 1024]);
    const float* wp = wp0 + k * 256;
#pragma unroll
    for (int j = 0; j < 16; ++j) acc[j] = fmaf(av, wp[j], acc[j]);
  }
#pragma unroll
  for (int j = 0; j < 16; ++j)
    part[(kc * 256 + jg * 16 + j) * 1024 + bg * 64 + lane] = acc[j];
}

// ---------------- fc1b: reduce 16 partials + bias + relu -> h_t[256][1024] ----------------
__global__ __launch_bounds__(256) void fc1b_k(const float* __restrict__ part,
                                              const float* __restrict__ bias,
                                              float* __restrict__ h) {
  int idx = blockIdx.x * 256 + threadIdx.x;   // j*1024 + b
  float s = bias[idx >> 10];
#pragma unroll
  for (int c = 0; c < 16; ++c) s += part[c * 262144 + idx];
  h[idx] = s > 0.f ? s : 0.f;
}

// ---------------- fc2 + softmax + dist/res (reads h_t[k][b]) ----------------
__global__ __launch_bounds__(256) void fc2_k(const float* __restrict__ h,     // [256][1024]
                                             const float* __restrict__ w,     // [256][51]
                                             const float* __restrict__ bias,
                                             const float* __restrict__ z,
                                             float* __restrict__ dist,        // [1024][6][51]
                                             float* __restrict__ res) {       // [1024][6]
  __shared__ float wl[256 * 51];
  const int tid = threadIdx.x;
#pragma unroll
  for (int i = tid; i < 256 * 51; i += 256) wl[i] = w[i];
  __syncthreads();

  const int j   = tid & 63;
  const int b   = blockIdx.x * 4 + RL(tid >> 6);
  const int jc = j < 51 ? j : 50;
  float acc = bias[jc];
#pragma unroll 8
  for (int k = 0; k < 256; ++k)
    acc = fmaf(h[k * 1024 + b], wl[k * 51 + jc], acc);
  float logit = (j < 51) ? acc : -1e30f;
  float m = logit;
#pragma unroll
  for (int o = 32; o > 0; o >>= 1) m = fmaxf(m, __shfl_xor(m, o, 64));
  float e = (j < 51) ? __expf(logit - m) : 0.f;
  float ssum = e;
#pragma unroll
  for (int o = 32; o > 0; o >>= 1) ssum += __shfl_xor(ssum, o, 64);
  float p = e / ssum;
  float zv = (j < 51) ? z[jc] : 0.f;
  float rz = p * zv;
#pragma unroll
  for (int o = 32; o > 0; o >>= 1) rz += __shfl_xor(rz, o, 64);
  if (j < 51) {
    float* db = dist + b * 6 * 51 + j;
#pragma unroll
    for (int n = 0; n < 6; ++n) db[n * 51] = p;
  }
  if (j < 6) res[b * 6 + j] = rz;
}

extern "C" void kernel_launch(void* const* d_in, const int* in_sizes, int n_in,
                              void* d_out, int out_size, void* d_ws, size_t ws_size,
                              hipStream_t stream) {
  const float* x   = (const float*)d_in[0];
  const float* cw1 = (const float*)d_in[1];
  const float* cb1 = (const float*)d_in[2];
  const float* cw2 = (const float*)d_in[3];
  const float* cb2 = (const float*)d_in[4];
  const float* cw3 = (const float*)d_in[5];
  const float* cb3 = (const float*)d_in[6];
  const float* fw1 = (const float*)d_in[7];
  const float* fb1 = (const float*)d_in[8];
  const float* fw2 = (const float*)d_in[9];
  const float* fb2 = (const float*)d_in[10];
  const float* z   = (const float*)d_in[11];

  float* ws = (float*)d_ws;
  // float-offsets (fp16 buffers occupy half):
  // c1h : [0, 6553600)          1024*12800 halfs
  // c1t : [6553600, 13107200)   12800*1024 halfs
  // c2t : [13107200, 15761408)  5184*1024 halfs
  // c3t : [15761408, 17367040)  3136*1024 halfs
  // part: [0, 4194304)          16*256*1024 fp32 (reuses dead c1h)
  // h_t : [4194304, 4456448)    256*1024 fp32
  __half* c1h = (__half*)ws;
  __half* c1t = (__half*)(ws + 6553600);
  __half* c2t = (__half*)(ws + 13107200);
  __half* c3t = (__half*)(ws + 15761408);
  float*  pw  = ws;
  float*  h_t = ws + 4194304;

  // Transposed conv weights in d_out scratch (77824 <= 319488); dist written last.
  float* wt2n = (float*)d_out;
  float* wt3n = (float*)d_out + 32768;
  float* wt1n = (float*)d_out + 69632;

  float* dist = (float*)d_out;
  float* res  = dist + 1024 * 6 * 51;

  wprep_k<<<144, 256, 0, stream>>>(cw1, cw2, cw3, wt1n, wt2n, wt3n);
  conv1_k<<<1024, 256, 0, stream>>>(x, wt1n, cb1, c1h);
  t1_k<<<dim3(200, 16), 256, 0, stream>>>(c1h, c1t);
  conv2_k<<<2304, 128, 0, stream>>>(c1t, wt2n, cb2, c2t);
  conv3_k<<<1792, 128, 0, stream>>>(c2t, wt3n, cb3, c3t);
  fc1a_k<<<4096, 64, 0, stream>>>(c3t, fw1, pw);
  fc1b_k<<<1024, 256, 0, stream>>>(pw, fb1, h_t);
  fc2_k<<<256, 256, 0, stream>>>(h_t, fw2, fb2, z, dist, res);
}

// Round 6
// 418.509 us; speedup vs baseline: 2.0886x; 1.1313x over previous
//
#include <hip/hip_runtime.h>
#include <hip/hip_fp16.h>

#define RL(x) __builtin_amdgcn_readfirstlane(x)

typedef _Float16 f16x8 __attribute__((ext_vector_type(8)));
typedef float    f32x16 __attribute__((ext_vector_type(16)));

// ---------------- weight prep ----------------
// wt1n[(ic*8+ky)*256 + g*64 + j*8 + kx] = w1[(g*8+j)*256 + ic*64 + ky*8 + kx]   (8192 fp32)
// w2h: fp16 MFMA-frag order: w2h[((ic*2+ot)*2+kh)*256 + ln*8 + j]
//      = w2[(ot*32+ln)*512 + ic*16 + ky*4 + kx],  k = kh*8+j, kx=k>>2, ky=k&3   (32768 halves)
// wt3n[((ic*3+ky)*8+ocg)*24 + o*3+kx] = w3[(ocg*8+o)*576 + ic*9 + ky*3 + kx]    (36864 fp32)
__global__ __launch_bounds__(256) void wprep_k(const float* __restrict__ w1,
                                               const float* __restrict__ w2,
                                               const float* __restrict__ w3,
                                               float* __restrict__ wt1,
                                               __half* __restrict__ w2h,
                                               float* __restrict__ wt3) {
  int i = blockIdx.x * 256 + threadIdx.x;
  if (i < 8192) {
    int kx = i & 7, j = (i >> 3) & 7, g = (i >> 6) & 3;
    int ky = (i >> 8) & 7, ic = i >> 11;
    wt1[i] = w1[(g * 8 + j) * 256 + ic * 64 + ky * 8 + kx];
  }
  if (i < 32768) {
    int j = i & 7, ln = (i >> 3) & 31, kh = (i >> 8) & 1, ot = (i >> 9) & 1, ic = i >> 10;
    int k = kh * 8 + j, kx = k >> 2, ky = k & 3, oc = ot * 32 + ln;
    w2h[i] = __float2half(w2[oc * 512 + ic * 16 + ky * 4 + kx]);
  }
  if (i < 36864) {
    int o3 = i % 24, o = o3 / 3, kx = o3 - o * 3;
    int r = i / 24, ocg = r & 7, r2 = r >> 3, ky = r2 % 3, ic = r2 / 3;
    wt3[i] = w3[(ocg * 8 + o) * 576 + ic * 9 + ky * 3 + kx];
  }
}

// ---------------- conv1: x[1024,4,84,84] -> c1h[b][32*400] fp16, k=8, s=4 ----------------
__global__ __launch_bounds__(256, 4) void conv1_k(const float* __restrict__ x,
                                                  const float* __restrict__ wt,   // wt1n
                                                  const float* __restrict__ bias,
                                                  __half* __restrict__ out) {
  __shared__ float plane[7056];          // one 84x84 fp32 ic-plane
  const int b    = blockIdx.x;
  const int tid  = threadIdx.x;
  const int lane = tid & 63;
  const int g    = RL(tid >> 6);

  int pv[7], ib[7];
#pragma unroll
  for (int s = 0; s < 7; ++s) {
    int p = lane + 64 * s;
    pv[s] = (p < 400);
    if (p > 399) p = 399;
    int py = p / 20, px = p - py * 20;
    ib[s] = py * 336 + px * 4;
  }

  float acc[7][8];
#pragma unroll
  for (int s = 0; s < 7; ++s)
#pragma unroll
    for (int j = 0; j < 8; ++j) acc[s][j] = 0.f;

  const float* xb = x + b * 28224;

#pragma unroll 1
  for (int ici = 0; ici < 4; ++ici) {
    const int ic = (ici + (b >> 8)) & 3;
    if (ici) __syncthreads();
    const float* xp = xb + ic * 7056;
#pragma unroll
    for (int i = 0; i < 7; ++i) {
      int idx = tid + i * 256;
      if (idx < 1764) {
        float4 v = *(const float4*)(xp + idx * 4);
        *(float4*)&plane[idx * 4] = v;
      }
    }
    __syncthreads();

#pragma unroll 1
    for (int ky = 0; ky < 8; ++ky) {
      const float* wp = wt + (ic * 8 + ky) * 256 + g * 64;
      float wr[8][8];
#pragma unroll
      for (int j = 0; j < 8; ++j) {
        float4 w0 = *(const float4*)(wp + j * 8);
        float4 w1 = *(const float4*)(wp + j * 8 + 4);
        wr[j][0]=w0.x; wr[j][1]=w0.y; wr[j][2]=w0.z; wr[j][3]=w0.w;
        wr[j][4]=w1.x; wr[j][5]=w1.y; wr[j][6]=w1.z; wr[j][7]=w1.w;
      }
      const float* rp = plane + ky * 84;
#pragma unroll
      for (int s = 0; s < 7; ++s) {
        float4 a = *(const float4*)(rp + ib[s]);
        float4 c = *(const float4*)(rp + ib[s] + 4);
        float in8[8] = {a.x, a.y, a.z, a.w, c.x, c.y, c.z, c.w};
#pragma unroll
        for (int j = 0; j < 8; ++j)
#pragma unroll
          for (int kx = 0; kx < 8; ++kx)
            acc[s][j] = fmaf(in8[kx], wr[j][kx], acc[s][j]);
      }
    }
  }

  const float inv256 = 1.0f / 256.0f;
#pragma unroll
  for (int j = 0; j < 8; ++j) {
    float bj = bias[g * 8 + j];
    __half* op = out + (b * 32 + g * 8 + j) * 400;
#pragma unroll
    for (int s = 0; s < 7; ++s) {
      if (pv[s]) {
        float v = acc[s][j] * inv256 + bj;
        op[lane + 64 * s] = __float2half(v > 0.f ? v : 0.f);
      }
    }
  }
}

// ---------------- t1: transpose c1h[1024][12800] -> c1t[12800][1024] (fp16) ----------------
__global__ __launch_bounds__(256) void t1_k(const __half* __restrict__ in,
                                            __half* __restrict__ out) {
  __shared__ __half t[64][65];
  const int kb = blockIdx.x * 64;
  const int bb = blockIdx.y * 64;
  const int lane = threadIdx.x & 63;
  const int ty   = threadIdx.x >> 6;
#pragma unroll
  for (int r = ty; r < 64; r += 4)
    t[r][lane] = in[(bb + r) * 12800 + kb + lane];
  __syncthreads();
#pragma unroll
  for (int r = ty; r < 64; r += 4)
    out[(kb + r) * 1024 + bb + lane] = t[lane][r];
}

// ---------------- conv2 (MFMA): c1t[12800][1024] -> c2t[5184][1024], k=4, s=2 -------------
// Per opy: C[64 oc][9 ox][64 b] = W[64][512] @ A[512][b] via mfma_f32_32x32x16_f16.
// 4 waves = (octile, bsub). Per-ic slab (80 contiguous c1t rows x 64 b) staged in LDS as
// [b][16 chunks of 8 halves], chunk phys = (px>>1)^(b&7) (XOR swizzle, both sides) so each
// B-frag is ONE conflict-free ds_read_b128; sliding window: chunk = ox + kh.
// W pre-packed in frag order by wprep; staged per-ic (1 KB) alongside. Double-buffered,
// loads issued early (T14). No per-thread __half arrays (R2 spill lesson).
__global__ __launch_bounds__(256, 1) void conv2_k(const __half* __restrict__ in,
                                                  const __half* __restrict__ w2h,
                                                  const float* __restrict__ bias,
                                                  __half* __restrict__ out) {
  __shared__ __align__(16) __half sh[2][9216];   // per buf: slab 8192 + W 1024 halves
  const int bid = blockIdx.x;          // 144 = 9 opy * 16 bt
  const int opy = bid % 9;
  const int bt  = bid / 9;
  const int bbase = bt * 64;
  const int tid  = threadIdx.x;
  const int lane = tid & 63;
  const int wv   = RL(tid >> 6);
  const int octile = wv & 1;
  const int bsub   = wv >> 1;
  const int kh = lane >> 5;            // k-half (0/1)
  const int ln = lane & 31;

  const unsigned short* inu = (const unsigned short*)in;
  const unsigned short* wu  = (const unsigned short*)w2h;

  // staging geometry: 5 passes; pass p covers (px = idx>>6, b = idx&63), idx = p*256+tid
  int roff[5], offA[5];
#pragma unroll
  for (int p = 0; p < 5; ++p) {
    int idx = p * 256 + tid;
    int px = idx >> 6, b = idx & 63;
    roff[p] = px * 1024 + b;                                   // ky stride = 20*1024
    offA[p] = b * 128 + ((((px >> 1) ^ (b & 7)) << 3) | ((px & 1) << 2));
  }
  const int base0 = (40 * opy) * 1024 + bbase;                 // within ic-plane

  f32x16 acc[9];
#pragma unroll
  for (int ox = 0; ox < 9; ++ox)
#pragma unroll
    for (int r = 0; r < 16; ++r) acc[ox][r] = 0.f;

  ushort4 s0, s1, s2, s3, s4; uint2 sW;

#define C2_LOAD(icv) do {                                                     \
    const unsigned short* ibp = inu + (icv) * 409600 + base0;                 \
    s0 = make_ushort4(ibp[roff[0]], ibp[roff[0]+20480], ibp[roff[0]+40960], ibp[roff[0]+61440]); \
    s1 = make_ushort4(ibp[roff[1]], ibp[roff[1]+20480], ibp[roff[1]+40960], ibp[roff[1]+61440]); \
    s2 = make_ushort4(ibp[roff[2]], ibp[roff[2]+20480], ibp[roff[2]+40960], ibp[roff[2]+61440]); \
    s3 = make_ushort4(ibp[roff[3]], ibp[roff[3]+20480], ibp[roff[3]+40960], ibp[roff[3]+61440]); \
    s4 = make_ushort4(ibp[roff[4]], ibp[roff[4]+20480], ibp[roff[4]+40960], ibp[roff[4]+61440]); \
    sW = *(const uint2*)(wu + (icv) * 1024 + tid * 4);                        \
  } while (0)

#define C2_STORE(buf) do {                                                    \
    *(uint2*)&sh[buf][offA[0]] = make_uint2((unsigned)s0.x | ((unsigned)s0.y << 16), (unsigned)s0.z | ((unsigned)s0.w << 16)); \
    *(uint2*)&sh[buf][offA[1]] = make_uint2((unsigned)s1.x | ((unsigned)s1.y << 16), (unsigned)s1.z | ((unsigned)s1.w << 16)); \
    *(uint2*)&sh[buf][offA[2]] = make_uint2((unsigned)s2.x | ((unsigned)s2.y << 16), (unsigned)s2.z | ((unsigned)s2.w << 16)); \
    *(uint2*)&sh[buf][offA[3]] = make_uint2((unsigned)s3.x | ((unsigned)s3.y << 16), (unsigned)s3.z | ((unsigned)s3.w << 16)); \
    *(uint2*)&sh[buf][offA[4]] = make_uint2((unsigned)s4.x | ((unsigned)s4.y << 16), (unsigned)s4.z | ((unsigned)s4.w << 16)); \
    *(uint2*)&sh[buf][8192 + tid * 4] = sW;                                   \
  } while (0)

  const int offW = 8192 + octile * 512 + kh * 256 + ln * 8;
  const int bloc = bsub * 32 + ln;
  const int bx7  = bloc & 7;
  const int brow = bloc * 128;

  int cur = 0;
  C2_LOAD(0);
#pragma unroll 1
  for (int ic = 0; ic < 32; ++ic) {
    __syncthreads();                       // prior reads of buf[cur] (2 iters ago) done
    C2_STORE(cur);
    const int icn = ic < 31 ? ic + 1 : 31;
    C2_LOAD(icn);                          // in flight during compute (T14)
    __syncthreads();                       // buf[cur] ready
    f16x8 aw = *(const f16x8*)&sh[cur][offW];
#pragma unroll
    for (int ox = 0; ox < 9; ++ox) {
      f16x8 bx = *(const f16x8*)&sh[cur][brow + (((ox + kh) ^ bx7) << 3)];
      acc[ox] = __builtin_amdgcn_mfma_f32_32x32x16_f16(aw, bx, acc[ox], 0, 0, 0);
    }
    cur ^= 1;
  }
#undef C2_LOAD
#undef C2_STORE

  // epilogue: C/D layout col=lane&31(b), row=(reg&3)+8*(reg>>2)+4*kh (oc)
  float bv[16];
#pragma unroll
  for (int r = 0; r < 16; ++r)
    bv[r] = bias[octile * 32 + (r & 3) + 8 * (r >> 2) + 4 * kh];
  const int bout = bbase + bloc;
#pragma unroll
  for (int ox = 0; ox < 9; ++ox) {
#pragma unroll
    for (int r = 0; r < 16; ++r) {
      const int oc = octile * 32 + (r & 3) + 8 * (r >> 2) + 4 * kh;
      float v = acc[ox][r] + bv[r];
      out[(oc * 81 + opy * 9 + ox) * 1024 + bout] = __float2half(v > 0.f ? v : 0.f);
    }
  }
}

// ---------------- conv3: c2t[5184][1024] -> c3t[3136][1024], k=3, s=1 (fp16 io) ----------
__global__ __launch_bounds__(128, 2) void conv3_k(const __half* __restrict__ in,
                                                  const float* __restrict__ wt,   // wt3n
                                                  const float* __restrict__ bias,
                                                  __half* __restrict__ out) {
  const int bid = blockIdx.x;            // 1792 = 128*(grp>>3) + 8*ocg + (grp&7)
  const int ocg = (bid >> 3) & 15;
  const int grp = ((bid >> 7) << 3) | (bid & 7);
  const int opy = grp % 7;
  const int bg  = grp / 7;
  const int tid  = threadIdx.x;
  const int lane = tid & 63;
  const int wv   = RL(tid >> 6);

  float acc[4][7];
#pragma unroll
  for (int o = 0; o < 4; ++o)
#pragma unroll
    for (int ox = 0; ox < 7; ++ox) acc[o][ox] = 0.f;

  const __half* ib = in + bg * 64 + lane;
  const int ic0 = wv * 32;

#pragma unroll 1
  for (int ici = 0; ici < 32; ++ici) {
    const int ic = ic0 + ici;
#pragma unroll
    for (int ky = 0; ky < 3; ++ky) {
      const float* wp = wt + ((ic * 3 + ky) * 8 + (ocg >> 1)) * 24 + (ocg & 1) * 12;
      float wk[12];
#pragma unroll
      for (int q = 0; q < 12; ++q) wk[q] = wp[q];
      const __half* rp = ib + (ic * 81 + (opy + ky) * 9) * 1024;
      float iv[9];
#pragma unroll
      for (int q = 0; q < 9; ++q) iv[q] = __half2float(rp[q * 1024]);
#pragma unroll
      for (int o = 0; o < 4; ++o)
#pragma unroll
        for (int ox = 0; ox < 7; ++ox)
#pragma unroll
          for (int kx = 0; kx < 3; ++kx)
            acc[o][ox] = fmaf(iv[ox + kx], wk[o * 3 + kx], acc[o][ox]);
    }
  }

  __shared__ float red[4][7][64];
  if (wv == 1) {
#pragma unroll
    for (int o = 0; o < 4; ++o)
#pragma unroll
      for (int ox = 0; ox < 7; ++ox) red[o][ox][lane] = acc[o][ox];
  }
  __syncthreads();
  if (wv == 0) {
#pragma unroll
    for (int o = 0; o < 4; ++o) {
      const int oc = ocg * 4 + o;
      const float bj = bias[oc];
#pragma unroll
      for (int ox = 0; ox < 7; ++ox) {
        float v = acc[o][ox] + red[o][ox][lane] + bj;
        out[(oc * 49 + opy * 7 + ox) * 1024 + bg * 64 + lane] =
            __float2half(v > 0.f ? v : 0.f);
      }
    }
  }
}

// ---------------- fc1a: c3t[3136][1024] @ fw1[3136][256] -> part[16][256][1024] -----------
__global__ __launch_bounds__(64, 2) void fc1a_k(const __half* __restrict__ a,
                                                const float* __restrict__ w,
                                                float* __restrict__ part) {
  const int bid = blockIdx.x;            // 4096 = 128*(grp>>3) + 8*jg + (grp&7)
  const int jg  = (bid >> 3) & 15;
  const int grp = ((bid >> 7) << 3) | (bid & 7);
  const int kc  = grp & 15;
  const int bg  = grp >> 4;
  const int lane = threadIdx.x;

  float acc[16];
#pragma unroll
  for (int j = 0; j < 16; ++j) acc[j] = 0.f;

  const __half* ap = a + kc * 196 * 1024 + bg * 64 + lane;
  const float* wp0 = w + kc * 196 * 256 + jg * 16;

#pragma unroll 4
  for (int k = 0; k < 196; ++k) {
    float av = __half2float(ap[k * 1024]);
    const float* wp = wp0 + k * 256;
#pragma unroll
    for (int j = 0; j < 16; ++j) acc[j] = fmaf(av, wp[j], acc[j]);
  }
#pragma unroll
  for (int j = 0; j < 16; ++j)
    part[(kc * 256 + jg * 16 + j) * 1024 + bg * 64 + lane] = acc[j];
}

// ---------------- fc1b: reduce 16 partials + bias + relu -> h_t[256][1024] ----------------
__global__ __launch_bounds__(256) void fc1b_k(const float* __restrict__ part,
                                              const float* __restrict__ bias,
                                              float* __restrict__ h) {
  int idx = blockIdx.x * 256 + threadIdx.x;   // j*1024 + b
  float s = bias[idx >> 10];
#pragma unroll
  for (int c = 0; c < 16; ++c) s += part[c * 262144 + idx];
  h[idx] = s > 0.f ? s : 0.f;
}

// ---------------- fc2 + softmax + dist/res (reads h_t[k][b]) ----------------
__global__ __launch_bounds__(256) void fc2_k(const float* __restrict__ h,     // [256][1024]
                                             const float* __restrict__ w,     // [256][51]
                                             const float* __restrict__ bias,
                                             const float* __restrict__ z,
                                             float* __restrict__ dist,        // [1024][6][51]
                                             float* __restrict__ res) {       // [1024][6]
  __shared__ float wl[256 * 51];
  const int tid = threadIdx.x;
#pragma unroll
  for (int i = tid; i < 256 * 51; i += 256) wl[i] = w[i];
  __syncthreads();

  const int j   = tid & 63;
  const int b   = blockIdx.x * 4 + RL(tid >> 6);
  const int jc = j < 51 ? j : 50;
  float acc = bias[jc];
#pragma unroll 8
  for (int k = 0; k < 256; ++k)
    acc = fmaf(h[k * 1024 + b], wl[k * 51 + jc], acc);
  float logit = (j < 51) ? acc : -1e30f;
  float m = logit;
#pragma unroll
  for (int o = 32; o > 0; o >>= 1) m = fmaxf(m, __shfl_xor(m, o, 64));
  float e = (j < 51) ? __expf(logit - m) : 0.f;
  float ssum = e;
#pragma unroll
  for (int o = 32; o > 0; o >>= 1) ssum += __shfl_xor(ssum, o, 64);
  float p = e / ssum;
  float zv = (j < 51) ? z[jc] : 0.f;
  float rz = p * zv;
#pragma unroll
  for (int o = 32; o > 0; o >>= 1) rz += __shfl_xor(rz, o, 64);
  if (j < 51) {
    float* db = dist + b * 6 * 51 + j;
#pragma unroll
    for (int n = 0; n < 6; ++n) db[n * 51] = p;
  }
  if (j < 6) res[b * 6 + j] = rz;
}

extern "C" void kernel_launch(void* const* d_in, const int* in_sizes, int n_in,
                              void* d_out, int out_size, void* d_ws, size_t ws_size,
                              hipStream_t stream) {
  const float* x   = (const float*)d_in[0];
  const float* cw1 = (const float*)d_in[1];
  const float* cb1 = (const float*)d_in[2];
  const float* cw2 = (const float*)d_in[3];
  const float* cb2 = (const float*)d_in[4];
  const float* cw3 = (const float*)d_in[5];
  const float* cb3 = (const float*)d_in[6];
  const float* fw1 = (const float*)d_in[7];
  const float* fb1 = (const float*)d_in[8];
  const float* fw2 = (const float*)d_in[9];
  const float* fb2 = (const float*)d_in[10];
  const float* z   = (const float*)d_in[11];

  float* ws = (float*)d_ws;
  // float-offsets (fp16 buffers occupy half):
  // c1h : [0, 6553600)          1024*12800 halfs
  // c1t : [6553600, 13107200)   12800*1024 halfs
  // c2t : [13107200, 15761408)  5184*1024 halfs
  // c3t : [15761408, 17367040)  3136*1024 halfs
  // part: [0, 4194304)          16*256*1024 fp32 (reuses dead c1h)
  // h_t : [4194304, 4456448)    256*1024 fp32
  __half* c1h = (__half*)ws;
  __half* c1t = (__half*)(ws + 6553600);
  __half* c2t = (__half*)(ws + 13107200);
  __half* c3t = (__half*)(ws + 15761408);
  float*  pw  = ws;
  float*  h_t = ws + 4194304;

  // Weight scratch in d_out (floats): wt3n [0,36864), wt1n [36864,45056),
  // w2h (halves) at float-offset 45056 .. 61440. dist written last (fc2).
  float*  wt3n = (float*)d_out;
  float*  wt1n = (float*)d_out + 36864;
  __half* w2h  = (__half*)((float*)d_out + 45056);

  float* dist = (float*)d_out;
  float* res  = dist + 1024 * 6 * 51;

  wprep_k<<<144, 256, 0, stream>>>(cw1, cw2, cw3, wt1n, w2h, wt3n);
  conv1_k<<<1024, 256, 0, stream>>>(x, wt1n, cb1, c1h);
  t1_k<<<dim3(200, 16), 256, 0, stream>>>(c1h, c1t);
  conv2_k<<<144, 256, 0, stream>>>(c1t, w2h, cb2, c2t);
  conv3_k<<<1792, 128, 0, stream>>>(c2t, wt3n, cb3, c3t);
  fc1a_k<<<4096, 64, 0, stream>>>(c3t, fw1, pw);
  fc1b_k<<<1024, 256, 0, stream>>>(pw, fb1, h_t);
  fc2_k<<<256, 256, 0, stream>>>(h_t, fw2, fb2, z, dist, res);
}